// Round 11
// baseline (448.452 us; speedup 1.0000x reference)
//
#include <hip/hip_runtime.h>
#include <stdint.h>

#define NB 4
#define NS 16384
#define ND 192
#define NE 8
#define NT 1024
#define NKP 256
#define NI 384
#define LNEPS 1e-5f

typedef __attribute__((ext_vector_type(8))) short bf16x8;
typedef __attribute__((ext_vector_type(4))) float f32x4;

__device__ __forceinline__ unsigned short f2bf(float f){
  unsigned u = __float_as_uint(f);
  u += 0x7FFFu + ((u >> 16) & 1u);
  return (unsigned short)(u >> 16);
}
__device__ __forceinline__ float bf2f(unsigned short s){
  return __uint_as_float((unsigned)s << 16);
}

__device__ __forceinline__ f32x4 MFMA(bf16x8 a, bf16x8 b, f32x4 c){
  return __builtin_amdgcn_mfma_f32_16x16x32_bf16(a, b, c, 0, 0, 0);
}

__device__ __forceinline__ void gload16(const void* g, void* l){
  __builtin_amdgcn_global_load_lds(
      (const __attribute__((address_space(1))) unsigned*)g,
      (__attribute__((address_space(3))) unsigned*)l, 16, 0, 0);
}

// ---------- K1: wave-per-token: stats + LN + gate softmax + xb16 emit ----------
// xb16[b][t] = 16 patch rows x 192 bf16, PRE-SWIZZLED: 4B word of (p, d..d+1) at
// byte p*384 + ((2d) ^ ((p&7)<<4)) — matches k_ffn's LDS read swizzle exactly.
__global__ __launch_bounds__(256) void k_stats(
    const float* __restrict__ x, const float* __restrict__ ln_g,
    const float* __restrict__ ln_b, const float* __restrict__ Wg,
    const float* __restrict__ Af, const float* __restrict__ cf,
    float* __restrict__ aff, unsigned short* __restrict__ xb16){
  int wv = threadIdx.x >> 6, lane = threadIdx.x & 63;
  int bt = blockIdx.x * 4 + wv;
  int b = bt >> 10, t = bt & (NT - 1);
  int th = t >> 5, tw = t & 31;
  const float* xb = x + (size_t)b * NS * ND;
  int rb = th * 512 + tw * 4;
  float v0[16], v1[16], v2[16];
  float s0 = 0.f, s1 = 0.f, s2 = 0.f, q0 = 0.f, q1 = 0.f, q2 = 0.f;
#pragma unroll
  for (int p = 0; p < 16; ++p){
    int srow = rb + (p >> 2) * 128 + (p & 3);
    const float* r = xb + (size_t)srow * ND;
    float f0 = r[lane], f1 = r[lane + 64], f2 = r[lane + 128];
    v0[p] = f0; v1[p] = f1; v2[p] = f2;
    s0 += f0; q0 += f0 * f0;
    s1 += f1; q1 += f1 * f1;
    s2 += f2; q2 += f2 * f2;
  }
  // emit xb16 (even lanes write packed (d, d+1) words, swizzled)
  {
    char* base = (char*)xb16 + (size_t)bt * 6144;
#pragma unroll
    for (int p = 0; p < 16; ++p){
      float n0 = __shfl_xor(v0[p], 1);
      float n1 = __shfl_xor(v1[p], 1);
      float n2 = __shfl_xor(v2[p], 1);
      if (!(lane & 1)){
        int key = (p & 7) << 4;
        unsigned w0 = (unsigned)f2bf(v0[p]) | ((unsigned)f2bf(n0) << 16);
        unsigned w1 = (unsigned)f2bf(v1[p]) | ((unsigned)f2bf(n1) << 16);
        unsigned w2 = (unsigned)f2bf(v2[p]) | ((unsigned)f2bf(n2) << 16);
        *(unsigned*)(base + p * 384 + (((0 * 128) + 2 * lane) ^ key)) = w0;
        *(unsigned*)(base + p * 384 + (((1 * 128) + 2 * lane) ^ key)) = w1;
        *(unsigned*)(base + p * 384 + (((2 * 128) + 2 * lane) ^ key)) = w2;
      }
    }
  }
  float m0 = s0 * 0.0625f, m1 = s1 * 0.0625f, m2 = s2 * 0.0625f;
  float pv0 = q0 * 0.0625f - m0 * m0;
  float pv1 = q1 * 0.0625f - m1 * m1;
  float pv2 = q2 * 0.0625f - m2 * m2;
  float msum = m0 + m1 + m2;
#pragma unroll
  for (int off = 32; off > 0; off >>= 1) msum += __shfl_xor(msum, off);
  float mu = msum * (1.f / 192.f);
  float d0 = m0 - mu, d1 = m1 - mu, d2 = m2 - mu;
  float vsum = d0 * d0 + d1 * d1 + d2 * d2;
#pragma unroll
  for (int off = 32; off > 0; off >>= 1) vsum += __shfl_xor(vsum, off);
  float inv = 1.0f / sqrtf(vsum * (1.f / 192.f) + LNEPS);
  float pl0 = d0 * inv * ln_g[lane] + ln_b[lane];
  float pl1 = d1 * inv * ln_g[lane + 64] + ln_b[lane + 64];
  float pl2 = d2 * inv * ln_g[lane + 128] + ln_b[lane + 128];
  float part[NE];
#pragma unroll
  for (int e = 0; e < NE; ++e){
    const float* wgr = Wg + e * 384;
    const float* afr = Af + e * ND;
    part[e] = pl0 * wgr[lane] + pv0 * afr[lane]
            + pl1 * wgr[lane + 64] + pv1 * afr[lane + 64]
            + pl2 * wgr[lane + 128] + pv2 * afr[lane + 128];
  }
#pragma unroll
  for (int e = 0; e < NE; ++e)
#pragma unroll
    for (int off = 32; off > 0; off >>= 1)
      part[e] += __shfl_xor(part[e], off);
  float lg[NE];
  float mx = -1e30f;
#pragma unroll
  for (int e = 0; e < NE; ++e){ lg[e] = part[e] + cf[e]; mx = fmaxf(mx, lg[e]); }
  float se = 0.f;
#pragma unroll
  for (int e = 0; e < NE; ++e) se += __expf(lg[e] - mx);
  float my = lg[0];
#pragma unroll
  for (int e = 1; e < NE; ++e) my = ((lane & 7) == e) ? lg[e] : my;
  if (lane < NE)
    aff[((size_t)b * NE + lane) * NT + t] = __expf(my - mx) / se;
}

// ---------- K2: weight prep (GU interleave 16-col + down bf16) + gate fold ----------
// wgu[e][c][k], c = 32*g + 16*s + r (r in 0..15) -> (s?Wup:Wgate)[e][16*g + r][k]
__global__ void k_wconv(const float* __restrict__ wg, const float* __restrict__ wu,
                        const float* __restrict__ wd, const float* __restrict__ Wc,
                        const float* __restrict__ Wgf, const float* __restrict__ bc,
                        const float* __restrict__ bg,
                        unsigned short* __restrict__ wgu, unsigned short* __restrict__ wdb,
                        float* __restrict__ Af, float* __restrict__ cf){
  int i = blockIdx.x * 256 + threadIdx.x;
  if (i < NE * 768 * ND){
    int e = i / (768 * ND);
    int rem = i - e * 768 * ND;
    int c = rem / ND;
    int k = rem - c * ND;
    int g = c >> 5, s = (c >> 4) & 1, r = c & 15;
    const float* src = s ? wu : wg;
    wgu[i] = f2bf(src[((size_t)(e * NI + g * 16 + r)) * ND + k]);
  }
  if (i < NE * ND * NI){
    wdb[i] = f2bf(wd[i]);
  }
  if (i < NE * ND){
    int e = i / ND, dd = i % ND;
    float s = 0.f;
    for (int dp = 0; dp < ND; ++dp) s += Wgf[e * 384 + ND + dp] * Wc[dp * ND + dd];
    Af[i] = s;
  }
  if (i < NE){
    float s = bg[i];
    for (int dp = 0; dp < ND; ++dp) s += bc[dp] * Wgf[i * 384 + ND + dp];
    cf[i] = s;
  }
}

// ---------- K4: exact-rank top-k + inverse index (parallelized: 4 blocks/be) ----------
__global__ __launch_bounds__(256) void k_topk(
    const float* __restrict__ aff, int* __restrict__ sidx,
    float* __restrict__ sval, float* __restrict__ twt,
    int* __restrict__ cnt, int* __restrict__ inv){
  int blk = blockIdx.x;
  int be = blk >> 2, q = blk & 3;
  int b = be >> 3, e = be & 7;
  __shared__ float vals[NT];
  reinterpret_cast<float4*>(vals)[threadIdx.x] =
      reinterpret_cast<const float4*>(aff + (size_t)be * NT)[threadIdx.x];
  __syncthreads();
  int t0 = q * 256 + threadIdx.x;
  float v0 = vals[t0];
  int r0 = 0;
  for (int j = 0; j < NT; j += 4){
    float4 vj = *reinterpret_cast<const float4*>(vals + j);
    r0 += (vj.x > v0) || (vj.x == v0 && (j + 0) < t0);
    r0 += (vj.y > v0) || (vj.y == v0 && (j + 1) < t0);
    r0 += (vj.z > v0) || (vj.z == v0 && (j + 2) < t0);
    r0 += (vj.w > v0) || (vj.w == v0 && (j + 3) < t0);
  }
  if (r0 < NKP){
    sidx[be * NKP + r0] = t0;
    sval[be * NKP + r0] = v0;
    atomicAdd(&twt[b * NT + t0], v0);
    int p = atomicAdd(&cnt[b * NT + t0], 1);
    inv[(b * NT + t0) * 8 + p] = (e << 16) | r0;
  }
}

// ---------- K6: expert FFN (R9 structure + 4-tile loop w/ gather-under-down) ----------
// 256 thr = 4 waves, block = one (b,e) x 4 tiles of 64 rows. LDS 72KB -> 2 blk/CU;
// grid (32,16) = 512 = exact resident set. stage(next) issued after the Hl-ready
// barrier (all Xl reads done) so gather latency hides under down+silu+store.
// Contrib stores NON-TEMPORAL (write-once; keeps L2 for weights).
__global__ __launch_bounds__(256) void k_ffn(
    const unsigned short* __restrict__ xb16, const unsigned short* __restrict__ wgu,
    const unsigned short* __restrict__ wdb,
    const int* __restrict__ sidx,
    unsigned short* __restrict__ contrib){
  int be = blockIdx.x, b = be >> 3, e = be & 7;
  int tid = threadIdx.x, w = tid >> 6, lane = tid & 63;
  int l15 = lane & 15, l4 = lane >> 4;
  __shared__ __align__(16) unsigned short Xl[64 * 192]; // pre-swizzled bf16
  __shared__ __align__(16) unsigned short Hl[64 * 384]; // swizzled bf16

  const char* xbp = (const char*)xb16;
  auto stage = [&](int jb){ // async gather: 6 x global_load_lds(16B)
#pragma unroll
    for (int i = 0; i < 6; ++i){
      int L = (i * 256 + tid) * 16;
      int j = L / 6144;
      int t = sidx[be * NKP + jb + j];
      gload16(xbp + (size_t)(b * NT + t) * 6144 + (L - j * 6144),
              (char*)Xl + L);
    }
  };

  stage(blockIdx.y * 16);

  for (int it = 0; it < 4; ++it){
    int tile = blockIdx.y * 4 + it;
    int jb = tile * 4;
    __syncthreads(); // drains vmcnt -> Xl staged; Hl free

    // ---- GU: C = X @ Wgu^T over interleaved 768 cols, 2 passes of 384
#pragma unroll
    for (int np = 0; np < 2; ++np){
      f32x4 acc[4][6];
#pragma unroll
      for (int mt = 0; mt < 4; ++mt)
#pragma unroll
        for (int nt = 0; nt < 6; ++nt) acc[mt][nt] = f32x4{0.f, 0.f, 0.f, 0.f};
#pragma unroll
      for (int ks = 0; ks < 6; ++ks){
        bf16x8 a[4];
#pragma unroll
        for (int mt = 0; mt < 4; ++mt){
          int row = mt * 16 + l15;
          int byte = row * 384 + ((ks * 64 + l4 * 16) ^ ((row & 7) << 4));
          a[mt] = *reinterpret_cast<const bf16x8*>(reinterpret_cast<const char*>(Xl) + byte);
        }
#pragma unroll
        for (int nt = 0; nt < 6; ++nt){
          int c = np * 384 + w * 96 + nt * 16 + l15;
          bf16x8 bb = *reinterpret_cast<const bf16x8*>(
              wgu + ((size_t)(e * 768 + c)) * ND + ks * 32 + l4 * 8);
#pragma unroll
          for (int mt = 0; mt < 4; ++mt)
            acc[mt][nt] = MFMA(a[mt], bb, acc[mt][nt]);
        }
      }
      // silu(G)*U -> bf16 -> swizzled Hl (nt even = gate, nt odd = up)
#pragma unroll
      for (int gp = 0; gp < 3; ++gp)
#pragma unroll
        for (int mt = 0; mt < 4; ++mt)
#pragma unroll
          for (int r = 0; r < 4; ++r){
            float g = acc[mt][2 * gp][r];
            float u = acc[mt][2 * gp + 1][r];
            float h = g * u / (1.f + __expf(-g));
            int hrow = mt * 16 + l4 * 4 + r;
            int hcol = np * 192 + w * 48 + gp * 16 + l15;
            int byte = hrow * 768 + ((hcol * 2) ^ ((hrow & 7) << 4));
            *reinterpret_cast<unsigned short*>(reinterpret_cast<char*>(Hl) + byte) = f2bf(h);
          }
    }
    __syncthreads(); // Hl ready AND all Xl reads complete

    // prefetch next tile into Xl: hides under down+silu+store
    if (it < 3) stage(jb + 4);

    // ---- down: O = H @ Wdown^T ; wave tile 64 x 48
    f32x4 ao[4][3];
#pragma unroll
    for (int mt = 0; mt < 4; ++mt)
#pragma unroll
      for (int nt = 0; nt < 3; ++nt) ao[mt][nt] = f32x4{0.f, 0.f, 0.f, 0.f};
#pragma unroll
    for (int ks = 0; ks < 12; ++ks){
      bf16x8 a[4];
#pragma unroll
      for (int mt = 0; mt < 4; ++mt){
        int row = mt * 16 + l15;
        int byte = row * 768 + ((ks * 64 + l4 * 16) ^ ((row & 7) << 4));
        a[mt] = *reinterpret_cast<const bf16x8*>(reinterpret_cast<const char*>(Hl) + byte);
      }
#pragma unroll
      for (int nt = 0; nt < 3; ++nt){
        int dcol = w * 48 + nt * 16 + l15;
        bf16x8 bd = *reinterpret_cast<const bf16x8*>(
            wdb + ((size_t)(e * ND + dcol)) * NI + ks * 32 + l4 * 8);
#pragma unroll
        for (int mt = 0; mt < 4; ++mt)
          ao[mt][nt] = MFMA(a[mt], bd, ao[mt][nt]);
      }
    }
    // ---- raw contrib store (bf16, non-temporal: write-once stream)
#pragma unroll
    for (int mt = 0; mt < 4; ++mt){
#pragma unroll
      for (int r = 0; r < 4; ++r){
        int mrow = tile * 64 + mt * 16 + l4 * 4 + r;
        unsigned short* dst = contrib + ((size_t)be * 4096 + mrow) * ND;
#pragma unroll
        for (int nt = 0; nt < 3; ++nt){
          int dcol = w * 48 + nt * 16 + l15;
          __builtin_nontemporal_store(f2bf(ao[mt][nt][r]), dst + dcol);
        }
      }
    }
  }
}

// ---------- K7: per-token weighted gather-sum of contributions -> out ----------
__global__ __launch_bounds__(256) void k_scatter(
    const unsigned short* __restrict__ contrib, const int* __restrict__ cnt,
    const int* __restrict__ inv, const float* __restrict__ sval,
    const float* __restrict__ twt, float* __restrict__ out){
  int bt = blockIdx.x;
  int b = bt >> 10, t = bt & (NT - 1);
  __shared__ int s_cnt;
  __shared__ int s_ent[8];
  __shared__ float s_wt[8];
  if (threadIdx.x == 0) s_cnt = cnt[bt];
  if (threadIdx.x < 8){
    int ent = inv[bt * 8 + threadIdx.x];
    s_ent[threadIdx.x] = ent;
    float tws = fmaxf(twt[bt], 1e-8f);
    int e = ent >> 16, r = ent & 0xffff;
    s_wt[threadIdx.x] = sval[((size_t)((b << 3) + e)) * NKP + r] / tws;
  }
  __syncthreads();
  int n = s_cnt;
  int p = threadIdx.x >> 4, dq = threadIdx.x & 15;
  int d0 = dq * 12;
  float acc[12];
#pragma unroll
  for (int i = 0; i < 12; ++i) acc[i] = 0.f;
  for (int i = 0; i < n; ++i){
    int ent = s_ent[i];
    int e = ent >> 16, r = ent & 0xffff;
    float wt = s_wt[i];
    const unsigned short* src = contrib +
        ((((size_t)((b * 8 + e) * NKP + r)) * 16 + p) * ND + d0);
#pragma unroll
    for (int c = 0; c < 3; ++c){
      uint2 v = *reinterpret_cast<const uint2*>(src + c * 4);
      acc[c * 4 + 0] += wt * bf2f((unsigned short)(v.x & 0xffff));
      acc[c * 4 + 1] += wt * bf2f((unsigned short)(v.x >> 16));
      acc[c * 4 + 2] += wt * bf2f((unsigned short)(v.y & 0xffff));
      acc[c * 4 + 3] += wt * bf2f((unsigned short)(v.y >> 16));
    }
  }
  int th = t >> 5, tw = t & 31;
  int srow = th * 512 + (p >> 2) * 128 + tw * 4 + (p & 3);
  float* dst = out + ((size_t)(b * NS + srow)) * ND + d0;
#pragma unroll
  for (int c = 0; c < 3; ++c){
    float4 o;
    o.x = acc[c * 4 + 0]; o.y = acc[c * 4 + 1];
    o.z = acc[c * 4 + 2]; o.w = acc[c * 4 + 3];
    *reinterpret_cast<float4*>(dst + c * 4) = o;
  }
}

extern "C" void kernel_launch(void* const* d_in, const int* in_sizes, int n_in,
                              void* d_out, int out_size, void* d_ws, size_t ws_size,
                              hipStream_t stream){
  const float* x     = (const float*)d_in[0];
  const float* ln_g  = (const float*)d_in[1];
  const float* ln_b  = (const float*)d_in[2];
  const float* Wc    = (const float*)d_in[3];
  const float* bc    = (const float*)d_in[4];
  const float* Wg    = (const float*)d_in[5];
  const float* bg    = (const float*)d_in[6];
  const float* Wgate = (const float*)d_in[7];
  const float* Wup   = (const float*)d_in[8];
  const float* Wdown = (const float*)d_in[9];
  float* out = (float*)d_out;
  (void)in_sizes; (void)n_in; (void)ws_size; (void)out_size;

  char* ws = (char*)d_ws;
  size_t o = 0;
  auto carve = [&](size_t bytes) -> char* {
    char* p = ws + o; o += (bytes + 255) & ~(size_t)255; return p;
  };
  float* aff  = (float*)carve((size_t)NB * NE * NT * 4);
  float* Af   = (float*)carve(NE * ND * 4);
  float* cf   = (float*)carve(256);
  int*   sidx = (int*)carve(NB * NE * NKP * 4);
  float* sval = (float*)carve(NB * NE * NKP * 4);
  float* twt  = (float*)carve(NB * NT * 4);
  int*   cnt  = (int*)carve(NB * NT * 4);
  int*   inv  = (int*)carve(NB * NT * 8 * 4);
  unsigned short* wgu  = (unsigned short*)carve((size_t)NE * 768 * ND * 2);
  unsigned short* wdb  = (unsigned short*)carve((size_t)NE * ND * NI * 2);
  unsigned short* xb16 = (unsigned short*)carve((size_t)NB * NT * 16 * ND * 2);
  unsigned short* contrib = (unsigned short*)carve((size_t)NB * NE * NKP * 16 * ND * 2);

  hipMemsetAsync(twt, 0, NB * NT * 4, stream);
  hipMemsetAsync(cnt, 0, NB * NT * 4, stream);

  k_wconv<<<(NE * 768 * ND + 255) / 256, 256, 0, stream>>>(
      Wgate, Wup, Wdown, Wc, Wg, bc, bg, wgu, wdb, Af, cf);
  k_stats<<<NB * NT / 4, 256, 0, stream>>>(x, ln_g, ln_b, Wg, Af, cf, aff, xb16);
  k_topk<<<NB * NE * 4, 256, 0, stream>>>(aff, sidx, sval, twt, cnt, inv);
  dim3 gffn(NB * NE, 16, 1);
  k_ffn<<<gffn, 256, 0, stream>>>(xb16, wgu, wdb, sidx, contrib);
  k_scatter<<<NB * NT, 256, 0, stream>>>(contrib, cnt, inv, sval, twt, out);
}

// Round 12
// 215.941 us; speedup vs baseline: 2.0767x; 2.0767x over previous
//
#include <hip/hip_runtime.h>
#include <stdint.h>

#define NB 4
#define NS 16384
#define ND 192
#define NE 8
#define NT 1024
#define NKP 256
#define NI 384
#define LNEPS 1e-5f

typedef __attribute__((ext_vector_type(8))) short bf16x8;
typedef __attribute__((ext_vector_type(4))) float f32x4;

__device__ __forceinline__ unsigned short f2bf(float f){
  unsigned u = __float_as_uint(f);
  u += 0x7FFFu + ((u >> 16) & 1u);
  return (unsigned short)(u >> 16);
}
__device__ __forceinline__ float bf2f(unsigned short s){
  return __uint_as_float((unsigned)s << 16);
}

__device__ __forceinline__ f32x4 MFMA(bf16x8 a, bf16x8 b, f32x4 c){
  return __builtin_amdgcn_mfma_f32_16x16x32_bf16(a, b, c, 0, 0, 0);
}

__device__ __forceinline__ void gload16(const void* g, void* l){
  __builtin_amdgcn_global_load_lds(
      (const __attribute__((address_space(1))) unsigned*)g,
      (__attribute__((address_space(3))) unsigned*)l, 16, 0, 0);
}

// ---------- K1: wave-per-token: stats + LN + gate softmax + xb16 emit ----------
// xb16[b][t] = 16 patch rows x 192 bf16, PRE-SWIZZLED: 4B word of (p, d..d+1) at
// byte p*384 + ((2d) ^ ((p&7)<<4)) — matches k_ffn's LDS read swizzle exactly.
// Also zero-inits twt/cnt (one wave per token; k_topk runs strictly after).
__global__ __launch_bounds__(256) void k_stats(
    const float* __restrict__ x, const float* __restrict__ ln_g,
    const float* __restrict__ ln_b, const float* __restrict__ Wg,
    const float* __restrict__ Af, const float* __restrict__ cf,
    float* __restrict__ aff, unsigned short* __restrict__ xb16,
    float* __restrict__ twt, int* __restrict__ cnt){
  int wv = threadIdx.x >> 6, lane = threadIdx.x & 63;
  int bt = blockIdx.x * 4 + wv;
  int b = bt >> 10, t = bt & (NT - 1);
  int th = t >> 5, tw = t & 31;
  if (lane == 8) twt[bt] = 0.f;
  if (lane == 9) cnt[bt] = 0;
  const float* xb = x + (size_t)b * NS * ND;
  int rb = th * 512 + tw * 4;
  float v0[16], v1[16], v2[16];
  float s0 = 0.f, s1 = 0.f, s2 = 0.f, q0 = 0.f, q1 = 0.f, q2 = 0.f;
#pragma unroll
  for (int p = 0; p < 16; ++p){
    int srow = rb + (p >> 2) * 128 + (p & 3);
    const float* r = xb + (size_t)srow * ND;
    float f0 = r[lane], f1 = r[lane + 64], f2 = r[lane + 128];
    v0[p] = f0; v1[p] = f1; v2[p] = f2;
    s0 += f0; q0 += f0 * f0;
    s1 += f1; q1 += f1 * f1;
    s2 += f2; q2 += f2 * f2;
  }
  // emit xb16 (even lanes write packed (d, d+1) words, swizzled)
  {
    char* base = (char*)xb16 + (size_t)bt * 6144;
#pragma unroll
    for (int p = 0; p < 16; ++p){
      float n0 = __shfl_xor(v0[p], 1);
      float n1 = __shfl_xor(v1[p], 1);
      float n2 = __shfl_xor(v2[p], 1);
      if (!(lane & 1)){
        int key = (p & 7) << 4;
        unsigned w0 = (unsigned)f2bf(v0[p]) | ((unsigned)f2bf(n0) << 16);
        unsigned w1 = (unsigned)f2bf(v1[p]) | ((unsigned)f2bf(n1) << 16);
        unsigned w2 = (unsigned)f2bf(v2[p]) | ((unsigned)f2bf(n2) << 16);
        *(unsigned*)(base + p * 384 + (((0 * 128) + 2 * lane) ^ key)) = w0;
        *(unsigned*)(base + p * 384 + (((1 * 128) + 2 * lane) ^ key)) = w1;
        *(unsigned*)(base + p * 384 + (((2 * 128) + 2 * lane) ^ key)) = w2;
      }
    }
  }
  float m0 = s0 * 0.0625f, m1 = s1 * 0.0625f, m2 = s2 * 0.0625f;
  float pv0 = q0 * 0.0625f - m0 * m0;
  float pv1 = q1 * 0.0625f - m1 * m1;
  float pv2 = q2 * 0.0625f - m2 * m2;
  float msum = m0 + m1 + m2;
#pragma unroll
  for (int off = 32; off > 0; off >>= 1) msum += __shfl_xor(msum, off);
  float mu = msum * (1.f / 192.f);
  float d0 = m0 - mu, d1 = m1 - mu, d2 = m2 - mu;
  float vsum = d0 * d0 + d1 * d1 + d2 * d2;
#pragma unroll
  for (int off = 32; off > 0; off >>= 1) vsum += __shfl_xor(vsum, off);
  float inv = 1.0f / sqrtf(vsum * (1.f / 192.f) + LNEPS);
  float pl0 = d0 * inv * ln_g[lane] + ln_b[lane];
  float pl1 = d1 * inv * ln_g[lane + 64] + ln_b[lane + 64];
  float pl2 = d2 * inv * ln_g[lane + 128] + ln_b[lane + 128];
  float part[NE];
#pragma unroll
  for (int e = 0; e < NE; ++e){
    const float* wgr = Wg + e * 384;
    const float* afr = Af + e * ND;
    part[e] = pl0 * wgr[lane] + pv0 * afr[lane]
            + pl1 * wgr[lane + 64] + pv1 * afr[lane + 64]
            + pl2 * wgr[lane + 128] + pv2 * afr[lane + 128];
  }
#pragma unroll
  for (int e = 0; e < NE; ++e)
#pragma unroll
    for (int off = 32; off > 0; off >>= 1)
      part[e] += __shfl_xor(part[e], off);
  float lg[NE];
  float mx = -1e30f;
#pragma unroll
  for (int e = 0; e < NE; ++e){ lg[e] = part[e] + cf[e]; mx = fmaxf(mx, lg[e]); }
  float se = 0.f;
#pragma unroll
  for (int e = 0; e < NE; ++e) se += __expf(lg[e] - mx);
  float my = lg[0];
#pragma unroll
  for (int e = 1; e < NE; ++e) my = ((lane & 7) == e) ? lg[e] : my;
  if (lane < NE)
    aff[((size_t)b * NE + lane) * NT + t] = __expf(my - mx) / se;
}

// ---------- K2: weight prep (GU interleave 16-col + down bf16) + gate fold ----------
// wgu[e][c][k], c = 32*g + 16*s + r (r in 0..15) -> (s?Wup:Wgate)[e][16*g + r][k]
__global__ void k_wconv(const float* __restrict__ wg, const float* __restrict__ wu,
                        const float* __restrict__ wd, const float* __restrict__ Wc,
                        const float* __restrict__ Wgf, const float* __restrict__ bc,
                        const float* __restrict__ bg,
                        unsigned short* __restrict__ wgu, unsigned short* __restrict__ wdb,
                        float* __restrict__ Af, float* __restrict__ cf){
  int i = blockIdx.x * 256 + threadIdx.x;
  if (i < NE * 768 * ND){
    int e = i / (768 * ND);
    int rem = i - e * 768 * ND;
    int c = rem / ND;
    int k = rem - c * ND;
    int g = c >> 5, s = (c >> 4) & 1, r = c & 15;
    const float* src = s ? wu : wg;
    wgu[i] = f2bf(src[((size_t)(e * NI + g * 16 + r)) * ND + k]);
  }
  if (i < NE * ND * NI){
    wdb[i] = f2bf(wd[i]);
  }
  if (i < NE * ND){
    int e = i / ND, dd = i % ND;
    float s = 0.f;
    for (int dp = 0; dp < ND; ++dp) s += Wgf[e * 384 + ND + dp] * Wc[dp * ND + dd];
    Af[i] = s;
  }
  if (i < NE){
    float s = bg[i];
    for (int dp = 0; dp < ND; ++dp) s += bc[dp] * Wgf[i * 384 + ND + dp];
    cf[i] = s;
  }
}

// ---------- K4: exact-rank top-k + inverse index (parallelized: 4 blocks/be) ----------
__global__ __launch_bounds__(256) void k_topk(
    const float* __restrict__ aff, int* __restrict__ sidx,
    float* __restrict__ sval, float* __restrict__ twt,
    int* __restrict__ cnt, int* __restrict__ inv){
  int blk = blockIdx.x;
  int be = blk >> 2, q = blk & 3;
  int b = be >> 3, e = be & 7;
  __shared__ float vals[NT];
  reinterpret_cast<float4*>(vals)[threadIdx.x] =
      reinterpret_cast<const float4*>(aff + (size_t)be * NT)[threadIdx.x];
  __syncthreads();
  int t0 = q * 256 + threadIdx.x;
  float v0 = vals[t0];
  int r0 = 0;
  for (int j = 0; j < NT; j += 4){
    float4 vj = *reinterpret_cast<const float4*>(vals + j);
    r0 += (vj.x > v0) || (vj.x == v0 && (j + 0) < t0);
    r0 += (vj.y > v0) || (vj.y == v0 && (j + 1) < t0);
    r0 += (vj.z > v0) || (vj.z == v0 && (j + 2) < t0);
    r0 += (vj.w > v0) || (vj.w == v0 && (j + 3) < t0);
  }
  if (r0 < NKP){
    sidx[be * NKP + r0] = t0;
    sval[be * NKP + r0] = v0;
    atomicAdd(&twt[b * NT + t0], v0);
    int p = atomicAdd(&cnt[b * NT + t0], 1);
    inv[(b * NT + t0) * 8 + p] = (e << 16) | r0;
  }
}

// ---------- K6: expert FFN (R9: 16x16 MFMA, 72KB LDS, async gather, nt stores) ----------
// 256 thr = 4 waves, one (b,e) x 64 rows. Gather = 6 x global_load_lds(16B) from
// pre-swizzled xb16. Contrib stores NON-TEMPORAL (write-once; keep L2 for weights).
__global__ __launch_bounds__(256) void k_ffn(
    const unsigned short* __restrict__ xb16, const unsigned short* __restrict__ wgu,
    const unsigned short* __restrict__ wdb,
    const int* __restrict__ sidx,
    unsigned short* __restrict__ contrib){
  int be = blockIdx.x, b = be >> 3, e = be & 7;
  int tile = blockIdx.y;
  int jb = tile * 4;
  int tid = threadIdx.x, w = tid >> 6, lane = tid & 63;
  int l15 = lane & 15, l4 = lane >> 4;
  __shared__ __align__(16) unsigned short Xl[64 * 192]; // pre-swizzled bf16
  __shared__ __align__(16) unsigned short Hl[64 * 384]; // swizzled bf16

  { // async gather: 6 x global_load_lds(16B); 384 loads/token = wave-aligned
    const char* xbp = (const char*)xb16;
#pragma unroll
    for (int i = 0; i < 6; ++i){
      int L = (i * 256 + tid) * 16;
      int j = L / 6144;
      int t = sidx[be * NKP + jb + j];
      gload16(xbp + (size_t)(b * NT + t) * 6144 + (L - j * 6144),
              (char*)Xl + L);
    }
  }
  __syncthreads();

  // ---- GU: C = X @ Wgu^T over interleaved 768 cols, 2 passes of 384
#pragma unroll
  for (int np = 0; np < 2; ++np){
    f32x4 acc[4][6];
#pragma unroll
    for (int mt = 0; mt < 4; ++mt)
#pragma unroll
      for (int nt = 0; nt < 6; ++nt) acc[mt][nt] = f32x4{0.f, 0.f, 0.f, 0.f};
#pragma unroll
    for (int ks = 0; ks < 6; ++ks){
      bf16x8 a[4];
#pragma unroll
      for (int mt = 0; mt < 4; ++mt){
        int row = mt * 16 + l15;
        int byte = row * 384 + ((ks * 64 + l4 * 16) ^ ((row & 7) << 4));
        a[mt] = *reinterpret_cast<const bf16x8*>(reinterpret_cast<const char*>(Xl) + byte);
      }
#pragma unroll
      for (int nt = 0; nt < 6; ++nt){
        int c = np * 384 + w * 96 + nt * 16 + l15;
        bf16x8 bb = *reinterpret_cast<const bf16x8*>(
            wgu + ((size_t)(e * 768 + c)) * ND + ks * 32 + l4 * 8);
#pragma unroll
        for (int mt = 0; mt < 4; ++mt)
          acc[mt][nt] = MFMA(a[mt], bb, acc[mt][nt]);
      }
    }
    // silu(G)*U -> bf16 -> swizzled Hl (nt even = gate, nt odd = up)
#pragma unroll
    for (int gp = 0; gp < 3; ++gp)
#pragma unroll
      for (int mt = 0; mt < 4; ++mt)
#pragma unroll
        for (int r = 0; r < 4; ++r){
          float g = acc[mt][2 * gp][r];
          float u = acc[mt][2 * gp + 1][r];
          float h = g * u / (1.f + __expf(-g));
          int hrow = mt * 16 + l4 * 4 + r;
          int hcol = np * 192 + w * 48 + gp * 16 + l15;
          int byte = hrow * 768 + ((hcol * 2) ^ ((hrow & 7) << 4));
          *reinterpret_cast<unsigned short*>(reinterpret_cast<char*>(Hl) + byte) = f2bf(h);
        }
  }
  __syncthreads();

  // ---- down: O = H @ Wdown^T ; wave tile 64 x 48
  f32x4 ao[4][3];
#pragma unroll
  for (int mt = 0; mt < 4; ++mt)
#pragma unroll
    for (int nt = 0; nt < 3; ++nt) ao[mt][nt] = f32x4{0.f, 0.f, 0.f, 0.f};
#pragma unroll
  for (int ks = 0; ks < 12; ++ks){
    bf16x8 a[4];
#pragma unroll
    for (int mt = 0; mt < 4; ++mt){
      int row = mt * 16 + l15;
      int byte = row * 768 + ((ks * 64 + l4 * 16) ^ ((row & 7) << 4));
      a[mt] = *reinterpret_cast<const bf16x8*>(reinterpret_cast<const char*>(Hl) + byte);
    }
#pragma unroll
    for (int nt = 0; nt < 3; ++nt){
      int dcol = w * 48 + nt * 16 + l15;
      bf16x8 bd = *reinterpret_cast<const bf16x8*>(
          wdb + ((size_t)(e * ND + dcol)) * NI + ks * 32 + l4 * 8);
#pragma unroll
      for (int mt = 0; mt < 4; ++mt)
        ao[mt][nt] = MFMA(a[mt], bd, ao[mt][nt]);
    }
  }
  // ---- raw contrib store (bf16, non-temporal: write-once stream)
#pragma unroll
  for (int mt = 0; mt < 4; ++mt){
#pragma unroll
    for (int r = 0; r < 4; ++r){
      int mrow = tile * 64 + mt * 16 + l4 * 4 + r;
      unsigned short* dst = contrib + ((size_t)be * 4096 + mrow) * ND;
#pragma unroll
      for (int nt = 0; nt < 3; ++nt){
        int dcol = w * 48 + nt * 16 + l15;
        __builtin_nontemporal_store(f2bf(ao[mt][nt][r]), dst + dcol);
      }
    }
  }
}

// ---------- K7: per-token weighted gather-sum of contributions -> out ----------
__global__ __launch_bounds__(256) void k_scatter(
    const unsigned short* __restrict__ contrib, const int* __restrict__ cnt,
    const int* __restrict__ inv, const float* __restrict__ sval,
    const float* __restrict__ twt, float* __restrict__ out){
  int bt = blockIdx.x;
  int b = bt >> 10, t = bt & (NT - 1);
  __shared__ int s_cnt;
  __shared__ int s_ent[8];
  __shared__ float s_wt[8];
  if (threadIdx.x == 0) s_cnt = cnt[bt];
  if (threadIdx.x < 8){
    int ent = inv[bt * 8 + threadIdx.x];
    s_ent[threadIdx.x] = ent;
    float tws = fmaxf(twt[bt], 1e-8f);
    int e = ent >> 16, r = ent & 0xffff;
    s_wt[threadIdx.x] = sval[((size_t)((b << 3) + e)) * NKP + r] / tws;
  }
  __syncthreads();
  int n = s_cnt;
  int p = threadIdx.x >> 4, dq = threadIdx.x & 15;
  int d0 = dq * 12;
  float acc[12];
#pragma unroll
  for (int i = 0; i < 12; ++i) acc[i] = 0.f;
  for (int i = 0; i < n; ++i){
    int ent = s_ent[i];
    int e = ent >> 16, r = ent & 0xffff;
    float wt = s_wt[i];
    const unsigned short* src = contrib +
        ((((size_t)((b * 8 + e) * NKP + r)) * 16 + p) * ND + d0);
#pragma unroll
    for (int c = 0; c < 3; ++c){
      uint2 v = *reinterpret_cast<const uint2*>(src + c * 4);
      acc[c * 4 + 0] += wt * bf2f((unsigned short)(v.x & 0xffff));
      acc[c * 4 + 1] += wt * bf2f((unsigned short)(v.x >> 16));
      acc[c * 4 + 2] += wt * bf2f((unsigned short)(v.y & 0xffff));
      acc[c * 4 + 3] += wt * bf2f((unsigned short)(v.y >> 16));
    }
  }
  int th = t >> 5, tw = t & 31;
  int srow = th * 512 + (p >> 2) * 128 + tw * 4 + (p & 3);
  float* dst = out + ((size_t)(b * NS + srow)) * ND + d0;
#pragma unroll
  for (int c = 0; c < 3; ++c){
    float4 o;
    o.x = acc[c * 4 + 0]; o.y = acc[c * 4 + 1];
    o.z = acc[c * 4 + 2]; o.w = acc[c * 4 + 3];
    *reinterpret_cast<float4*>(dst + c * 4) = o;
  }
}

extern "C" void kernel_launch(void* const* d_in, const int* in_sizes, int n_in,
                              void* d_out, int out_size, void* d_ws, size_t ws_size,
                              hipStream_t stream){
  const float* x     = (const float*)d_in[0];
  const float* ln_g  = (const float*)d_in[1];
  const float* ln_b  = (const float*)d_in[2];
  const float* Wc    = (const float*)d_in[3];
  const float* bc    = (const float*)d_in[4];
  const float* Wg    = (const float*)d_in[5];
  const float* bg    = (const float*)d_in[6];
  const float* Wgate = (const float*)d_in[7];
  const float* Wup   = (const float*)d_in[8];
  const float* Wdown = (const float*)d_in[9];
  float* out = (float*)d_out;
  (void)in_sizes; (void)n_in; (void)ws_size; (void)out_size;

  char* ws = (char*)d_ws;
  size_t o = 0;
  auto carve = [&](size_t bytes) -> char* {
    char* p = ws + o; o += (bytes + 255) & ~(size_t)255; return p;
  };
  float* aff  = (float*)carve((size_t)NB * NE * NT * 4);
  float* Af   = (float*)carve(NE * ND * 4);
  float* cf   = (float*)carve(256);
  int*   sidx = (int*)carve(NB * NE * NKP * 4);
  float* sval = (float*)carve(NB * NE * NKP * 4);
  float* twt  = (float*)carve(NB * NT * 4);
  int*   cnt  = (int*)carve(NB * NT * 4);
  int*   inv  = (int*)carve(NB * NT * 8 * 4);
  unsigned short* wgu  = (unsigned short*)carve((size_t)NE * 768 * ND * 2);
  unsigned short* wdb  = (unsigned short*)carve((size_t)NE * ND * NI * 2);
  unsigned short* xb16 = (unsigned short*)carve((size_t)NB * NT * 16 * ND * 2);
  unsigned short* contrib = (unsigned short*)carve((size_t)NB * NE * NKP * 16 * ND * 2);

  k_wconv<<<(NE * 768 * ND + 255) / 256, 256, 0, stream>>>(
      Wgate, Wup, Wdown, Wc, Wg, bc, bg, wgu, wdb, Af, cf);
  k_stats<<<NB * NT / 4, 256, 0, stream>>>(x, ln_g, ln_b, Wg, Af, cf, aff, xb16, twt, cnt);
  k_topk<<<NB * NE * 4, 256, 0, stream>>>(aff, sidx, sval, twt, cnt, inv);
  dim3 gffn(NB * NE, 4096 / 64, 1);
  k_ffn<<<gffn, 256, 0, stream>>>(xb16, wgu, wdb, sidx, contrib);
  k_scatter<<<NB * NT, 256, 0, stream>>>(contrib, cnt, inv, sval, twt, out);
}

// Round 13
// 212.565 us; speedup vs baseline: 2.1097x; 1.0159x over previous
//
#include <hip/hip_runtime.h>
#include <stdint.h>

#define NB 4
#define NS 16384
#define ND 192
#define NE 8
#define NT 1024
#define NKP 256
#define NI 384
#define LNEPS 1e-5f

typedef __attribute__((ext_vector_type(8))) short bf16x8;
typedef __attribute__((ext_vector_type(4))) float f32x4;

__device__ __forceinline__ unsigned short f2bf(float f){
  unsigned u = __float_as_uint(f);
  u += 0x7FFFu + ((u >> 16) & 1u);
  return (unsigned short)(u >> 16);
}
__device__ __forceinline__ float bf2f(unsigned short s){
  return __uint_as_float((unsigned)s << 16);
}

__device__ __forceinline__ f32x4 MFMA(bf16x8 a, bf16x8 b, f32x4 c){
  return __builtin_amdgcn_mfma_f32_16x16x32_bf16(a, b, c, 0, 0, 0);
}

__device__ __forceinline__ void gload16(const void* g, void* l){
  __builtin_amdgcn_global_load_lds(
      (const __attribute__((address_space(1))) unsigned*)g,
      (__attribute__((address_space(3))) unsigned*)l, 16, 0, 0);
}

// ---------- K1: wave-per-token: stats + LN + gate softmax + xb16 emit ----------
// xb16[b][t] = 16 patch rows x 192 bf16, PRE-SWIZZLED: 4B word of (p, d..d+1) at
// byte p*384 + ((2d) ^ ((p&7)<<4)) — matches k_ffn's LDS read swizzle exactly.
// Also zero-inits twt/cnt (one wave per token; k_topk runs strictly after).
__global__ __launch_bounds__(256) void k_stats(
    const float* __restrict__ x, const float* __restrict__ ln_g,
    const float* __restrict__ ln_b, const float* __restrict__ Wg,
    const float* __restrict__ Af, const float* __restrict__ cf,
    float* __restrict__ aff, unsigned short* __restrict__ xb16,
    float* __restrict__ twt, int* __restrict__ cnt){
  int wv = threadIdx.x >> 6, lane = threadIdx.x & 63;
  int bt = blockIdx.x * 4 + wv;
  int b = bt >> 10, t = bt & (NT - 1);
  int th = t >> 5, tw = t & 31;
  if (lane == 8) twt[bt] = 0.f;
  if (lane == 9) cnt[bt] = 0;
  const float* xb = x + (size_t)b * NS * ND;
  int rb = th * 512 + tw * 4;
  float v0[16], v1[16], v2[16];
  float s0 = 0.f, s1 = 0.f, s2 = 0.f, q0 = 0.f, q1 = 0.f, q2 = 0.f;
#pragma unroll
  for (int p = 0; p < 16; ++p){
    int srow = rb + (p >> 2) * 128 + (p & 3);
    const float* r = xb + (size_t)srow * ND;
    float f0 = r[lane], f1 = r[lane + 64], f2 = r[lane + 128];
    v0[p] = f0; v1[p] = f1; v2[p] = f2;
    s0 += f0; q0 += f0 * f0;
    s1 += f1; q1 += f1 * f1;
    s2 += f2; q2 += f2 * f2;
  }
  // emit xb16 (even lanes write packed (d, d+1) words, swizzled)
  {
    char* base = (char*)xb16 + (size_t)bt * 6144;
#pragma unroll
    for (int p = 0; p < 16; ++p){
      float n0 = __shfl_xor(v0[p], 1);
      float n1 = __shfl_xor(v1[p], 1);
      float n2 = __shfl_xor(v2[p], 1);
      if (!(lane & 1)){
        int key = (p & 7) << 4;
        unsigned w0 = (unsigned)f2bf(v0[p]) | ((unsigned)f2bf(n0) << 16);
        unsigned w1 = (unsigned)f2bf(v1[p]) | ((unsigned)f2bf(n1) << 16);
        unsigned w2 = (unsigned)f2bf(v2[p]) | ((unsigned)f2bf(n2) << 16);
        *(unsigned*)(base + p * 384 + (((0 * 128) + 2 * lane) ^ key)) = w0;
        *(unsigned*)(base + p * 384 + (((1 * 128) + 2 * lane) ^ key)) = w1;
        *(unsigned*)(base + p * 384 + (((2 * 128) + 2 * lane) ^ key)) = w2;
      }
    }
  }
  float m0 = s0 * 0.0625f, m1 = s1 * 0.0625f, m2 = s2 * 0.0625f;
  float pv0 = q0 * 0.0625f - m0 * m0;
  float pv1 = q1 * 0.0625f - m1 * m1;
  float pv2 = q2 * 0.0625f - m2 * m2;
  float msum = m0 + m1 + m2;
#pragma unroll
  for (int off = 32; off > 0; off >>= 1) msum += __shfl_xor(msum, off);
  float mu = msum * (1.f / 192.f);
  float d0 = m0 - mu, d1 = m1 - mu, d2 = m2 - mu;
  float vsum = d0 * d0 + d1 * d1 + d2 * d2;
#pragma unroll
  for (int off = 32; off > 0; off >>= 1) vsum += __shfl_xor(vsum, off);
  float inv = 1.0f / sqrtf(vsum * (1.f / 192.f) + LNEPS);
  float pl0 = d0 * inv * ln_g[lane] + ln_b[lane];
  float pl1 = d1 * inv * ln_g[lane + 64] + ln_b[lane + 64];
  float pl2 = d2 * inv * ln_g[lane + 128] + ln_b[lane + 128];
  float part[NE];
#pragma unroll
  for (int e = 0; e < NE; ++e){
    const float* wgr = Wg + e * 384;
    const float* afr = Af + e * ND;
    part[e] = pl0 * wgr[lane] + pv0 * afr[lane]
            + pl1 * wgr[lane + 64] + pv1 * afr[lane + 64]
            + pl2 * wgr[lane + 128] + pv2 * afr[lane + 128];
  }
#pragma unroll
  for (int e = 0; e < NE; ++e)
#pragma unroll
    for (int off = 32; off > 0; off >>= 1)
      part[e] += __shfl_xor(part[e], off);
  float lg[NE];
  float mx = -1e30f;
#pragma unroll
  for (int e = 0; e < NE; ++e){ lg[e] = part[e] + cf[e]; mx = fmaxf(mx, lg[e]); }
  float se = 0.f;
#pragma unroll
  for (int e = 0; e < NE; ++e) se += __expf(lg[e] - mx);
  float my = lg[0];
#pragma unroll
  for (int e = 1; e < NE; ++e) my = ((lane & 7) == e) ? lg[e] : my;
  if (lane < NE)
    aff[((size_t)b * NE + lane) * NT + t] = __expf(my - mx) / se;
}

// ---------- K2: weight prep (GU interleave 16-col + down bf16) + gate fold ----------
// wgu[e][c][k], c = 32*g + 16*s + r (r in 0..15) -> (s?Wup:Wgate)[e][16*g + r][k]
__global__ void k_wconv(const float* __restrict__ wg, const float* __restrict__ wu,
                        const float* __restrict__ wd, const float* __restrict__ Wc,
                        const float* __restrict__ Wgf, const float* __restrict__ bc,
                        const float* __restrict__ bg,
                        unsigned short* __restrict__ wgu, unsigned short* __restrict__ wdb,
                        float* __restrict__ Af, float* __restrict__ cf){
  int i = blockIdx.x * 256 + threadIdx.x;
  if (i < NE * 768 * ND){
    int e = i / (768 * ND);
    int rem = i - e * 768 * ND;
    int c = rem / ND;
    int k = rem - c * ND;
    int g = c >> 5, s = (c >> 4) & 1, r = c & 15;
    const float* src = s ? wu : wg;
    wgu[i] = f2bf(src[((size_t)(e * NI + g * 16 + r)) * ND + k]);
  }
  if (i < NE * ND * NI){
    wdb[i] = f2bf(wd[i]);
  }
  if (i < NE * ND){
    int e = i / ND, dd = i % ND;
    float s = 0.f;
    for (int dp = 0; dp < ND; ++dp) s += Wgf[e * 384 + ND + dp] * Wc[dp * ND + dd];
    Af[i] = s;
  }
  if (i < NE){
    float s = bg[i];
    for (int dp = 0; dp < ND; ++dp) s += bc[dp] * Wgf[i * 384 + ND + dp];
    cf[i] = s;
  }
}

// ---------- K4: exact-rank top-k + inverse index (parallelized: 4 blocks/be) ----------
__global__ __launch_bounds__(256) void k_topk(
    const float* __restrict__ aff, int* __restrict__ sidx,
    float* __restrict__ sval, float* __restrict__ twt,
    int* __restrict__ cnt, int* __restrict__ inv){
  int blk = blockIdx.x;
  int be = blk >> 2, q = blk & 3;
  int b = be >> 3, e = be & 7;
  __shared__ float vals[NT];
  reinterpret_cast<float4*>(vals)[threadIdx.x] =
      reinterpret_cast<const float4*>(aff + (size_t)be * NT)[threadIdx.x];
  __syncthreads();
  int t0 = q * 256 + threadIdx.x;
  float v0 = vals[t0];
  int r0 = 0;
  for (int j = 0; j < NT; j += 4){
    float4 vj = *reinterpret_cast<const float4*>(vals + j);
    r0 += (vj.x > v0) || (vj.x == v0 && (j + 0) < t0);
    r0 += (vj.y > v0) || (vj.y == v0 && (j + 1) < t0);
    r0 += (vj.z > v0) || (vj.z == v0 && (j + 2) < t0);
    r0 += (vj.w > v0) || (vj.w == v0 && (j + 3) < t0);
  }
  if (r0 < NKP){
    sidx[be * NKP + r0] = t0;
    sval[be * NKP + r0] = v0;
    atomicAdd(&twt[b * NT + t0], v0);
    int p = atomicAdd(&cnt[b * NT + t0], 1);
    inv[(b * NT + t0) * 8 + p] = (e << 16) | r0;
  }
}

// ---------- K6: expert FFN (R9: 16x16 MFMA, 72KB LDS, async gather, nt stores) ----------
// 256 thr = 4 waves, one (b,e) x 64 rows. Gather = 6 x global_load_lds(16B) from
// pre-swizzled xb16. silu uses v_rcp_f32 (IEEE div is ~10 VALU ops; rcp err << bf16).
// Contrib stores NON-TEMPORAL (write-once; keep L2 for weights).
__global__ __launch_bounds__(256) void k_ffn(
    const unsigned short* __restrict__ xb16, const unsigned short* __restrict__ wgu,
    const unsigned short* __restrict__ wdb,
    const int* __restrict__ sidx,
    unsigned short* __restrict__ contrib){
  int be = blockIdx.x, b = be >> 3, e = be & 7;
  int tile = blockIdx.y;
  int jb = tile * 4;
  int tid = threadIdx.x, w = tid >> 6, lane = tid & 63;
  int l15 = lane & 15, l4 = lane >> 4;
  __shared__ __align__(16) unsigned short Xl[64 * 192]; // pre-swizzled bf16
  __shared__ __align__(16) unsigned short Hl[64 * 384]; // swizzled bf16

  { // async gather: 6 x global_load_lds(16B); 384 loads/token = wave-aligned
    const char* xbp = (const char*)xb16;
#pragma unroll
    for (int i = 0; i < 6; ++i){
      int L = (i * 256 + tid) * 16;
      int j = L / 6144;
      int t = sidx[be * NKP + jb + j];
      gload16(xbp + (size_t)(b * NT + t) * 6144 + (L - j * 6144),
              (char*)Xl + L);
    }
  }
  __syncthreads();

  // ---- GU: C = X @ Wgu^T over interleaved 768 cols, 2 passes of 384
#pragma unroll
  for (int np = 0; np < 2; ++np){
    f32x4 acc[4][6];
#pragma unroll
    for (int mt = 0; mt < 4; ++mt)
#pragma unroll
      for (int nt = 0; nt < 6; ++nt) acc[mt][nt] = f32x4{0.f, 0.f, 0.f, 0.f};
#pragma unroll
    for (int ks = 0; ks < 6; ++ks){
      bf16x8 a[4];
#pragma unroll
      for (int mt = 0; mt < 4; ++mt){
        int row = mt * 16 + l15;
        int byte = row * 384 + ((ks * 64 + l4 * 16) ^ ((row & 7) << 4));
        a[mt] = *reinterpret_cast<const bf16x8*>(reinterpret_cast<const char*>(Xl) + byte);
      }
#pragma unroll
      for (int nt = 0; nt < 6; ++nt){
        int c = np * 384 + w * 96 + nt * 16 + l15;
        bf16x8 bb = *reinterpret_cast<const bf16x8*>(
            wgu + ((size_t)(e * 768 + c)) * ND + ks * 32 + l4 * 8);
#pragma unroll
        for (int mt = 0; mt < 4; ++mt)
          acc[mt][nt] = MFMA(a[mt], bb, acc[mt][nt]);
      }
    }
    // silu(G)*U -> bf16 -> swizzled Hl (nt even = gate, nt odd = up)
#pragma unroll
    for (int gp = 0; gp < 3; ++gp)
#pragma unroll
      for (int mt = 0; mt < 4; ++mt)
#pragma unroll
        for (int r = 0; r < 4; ++r){
          float g = acc[mt][2 * gp][r];
          float u = acc[mt][2 * gp + 1][r];
          float h = g * u * __builtin_amdgcn_rcpf(1.f + __expf(-g));
          int hrow = mt * 16 + l4 * 4 + r;
          int hcol = np * 192 + w * 48 + gp * 16 + l15;
          int byte = hrow * 768 + ((hcol * 2) ^ ((hrow & 7) << 4));
          *reinterpret_cast<unsigned short*>(reinterpret_cast<char*>(Hl) + byte) = f2bf(h);
        }
  }
  __syncthreads();

  // ---- down: O = H @ Wdown^T ; wave tile 64 x 48
  f32x4 ao[4][3];
#pragma unroll
  for (int mt = 0; mt < 4; ++mt)
#pragma unroll
    for (int nt = 0; nt < 3; ++nt) ao[mt][nt] = f32x4{0.f, 0.f, 0.f, 0.f};
#pragma unroll
  for (int ks = 0; ks < 12; ++ks){
    bf16x8 a[4];
#pragma unroll
    for (int mt = 0; mt < 4; ++mt){
      int row = mt * 16 + l15;
      int byte = row * 768 + ((ks * 64 + l4 * 16) ^ ((row & 7) << 4));
      a[mt] = *reinterpret_cast<const bf16x8*>(reinterpret_cast<const char*>(Hl) + byte);
    }
#pragma unroll
    for (int nt = 0; nt < 3; ++nt){
      int dcol = w * 48 + nt * 16 + l15;
      bf16x8 bd = *reinterpret_cast<const bf16x8*>(
          wdb + ((size_t)(e * ND + dcol)) * NI + ks * 32 + l4 * 8);
#pragma unroll
      for (int mt = 0; mt < 4; ++mt)
        ao[mt][nt] = MFMA(a[mt], bd, ao[mt][nt]);
    }
  }
  // ---- raw contrib store (bf16, non-temporal: write-once stream)
#pragma unroll
  for (int mt = 0; mt < 4; ++mt){
#pragma unroll
    for (int r = 0; r < 4; ++r){
      int mrow = tile * 64 + mt * 16 + l4 * 4 + r;
      unsigned short* dst = contrib + ((size_t)be * 4096 + mrow) * ND;
#pragma unroll
      for (int nt = 0; nt < 3; ++nt){
        int dcol = w * 48 + nt * 16 + l15;
        __builtin_nontemporal_store(f2bf(ao[mt][nt][r]), dst + dcol);
      }
    }
  }
}

// ---------- K7: per-token weighted gather-sum of contributions -> out ----------
__global__ __launch_bounds__(256) void k_scatter(
    const unsigned short* __restrict__ contrib, const int* __restrict__ cnt,
    const int* __restrict__ inv, const float* __restrict__ sval,
    const float* __restrict__ twt, float* __restrict__ out){
  int bt = blockIdx.x;
  int b = bt >> 10, t = bt & (NT - 1);
  __shared__ int s_cnt;
  __shared__ int s_ent[8];
  __shared__ float s_wt[8];
  if (threadIdx.x == 0) s_cnt = cnt[bt];
  if (threadIdx.x < 8){
    int ent = inv[bt * 8 + threadIdx.x];
    s_ent[threadIdx.x] = ent;
    float tws = fmaxf(twt[bt], 1e-8f);
    int e = ent >> 16, r = ent & 0xffff;
    s_wt[threadIdx.x] = sval[((size_t)((b << 3) + e)) * NKP + r] / tws;
  }
  __syncthreads();
  int n = s_cnt;
  int p = threadIdx.x >> 4, dq = threadIdx.x & 15;
  int d0 = dq * 12;
  float acc[12];
#pragma unroll
  for (int i = 0; i < 12; ++i) acc[i] = 0.f;
  for (int i = 0; i < n; ++i){
    int ent = s_ent[i];
    int e = ent >> 16, r = ent & 0xffff;
    float wt = s_wt[i];
    const unsigned short* src = contrib +
        ((((size_t)((b * 8 + e) * NKP + r)) * 16 + p) * ND + d0);
#pragma unroll
    for (int c = 0; c < 3; ++c){
      uint2 v = *reinterpret_cast<const uint2*>(src + c * 4);
      acc[c * 4 + 0] += wt * bf2f((unsigned short)(v.x & 0xffff));
      acc[c * 4 + 1] += wt * bf2f((unsigned short)(v.x >> 16));
      acc[c * 4 + 2] += wt * bf2f((unsigned short)(v.y & 0xffff));
      acc[c * 4 + 3] += wt * bf2f((unsigned short)(v.y >> 16));
    }
  }
  int th = t >> 5, tw = t & 31;
  int srow = th * 512 + (p >> 2) * 128 + tw * 4 + (p & 3);
  float* dst = out + ((size_t)(b * NS + srow)) * ND + d0;
#pragma unroll
  for (int c = 0; c < 3; ++c){
    float4 o;
    o.x = acc[c * 4 + 0]; o.y = acc[c * 4 + 1];
    o.z = acc[c * 4 + 2]; o.w = acc[c * 4 + 3];
    *reinterpret_cast<float4*>(dst + c * 4) = o;
  }
}

extern "C" void kernel_launch(void* const* d_in, const int* in_sizes, int n_in,
                              void* d_out, int out_size, void* d_ws, size_t ws_size,
                              hipStream_t stream){
  const float* x     = (const float*)d_in[0];
  const float* ln_g  = (const float*)d_in[1];
  const float* ln_b  = (const float*)d_in[2];
  const float* Wc    = (const float*)d_in[3];
  const float* bc    = (const float*)d_in[4];
  const float* Wg    = (const float*)d_in[5];
  const float* bg    = (const float*)d_in[6];
  const float* Wgate = (const float*)d_in[7];
  const float* Wup   = (const float*)d_in[8];
  const float* Wdown = (const float*)d_in[9];
  float* out = (float*)d_out;
  (void)in_sizes; (void)n_in; (void)ws_size; (void)out_size;

  char* ws = (char*)d_ws;
  size_t o = 0;
  auto carve = [&](size_t bytes) -> char* {
    char* p = ws + o; o += (bytes + 255) & ~(size_t)255; return p;
  };
  float* aff  = (float*)carve((size_t)NB * NE * NT * 4);
  float* Af   = (float*)carve(NE * ND * 4);
  float* cf   = (float*)carve(256);
  int*   sidx = (int*)carve(NB * NE * NKP * 4);
  float* sval = (float*)carve(NB * NE * NKP * 4);
  float* twt  = (float*)carve(NB * NT * 4);
  int*   cnt  = (int*)carve(NB * NT * 4);
  int*   inv  = (int*)carve(NB * NT * 8 * 4);
  unsigned short* wgu  = (unsigned short*)carve((size_t)NE * 768 * ND * 2);
  unsigned short* wdb  = (unsigned short*)carve((size_t)NE * ND * NI * 2);
  unsigned short* xb16 = (unsigned short*)carve((size_t)NB * NT * 16 * ND * 2);
  unsigned short* contrib = (unsigned short*)carve((size_t)NB * NE * NKP * 16 * ND * 2);

  k_wconv<<<(NE * 768 * ND + 255) / 256, 256, 0, stream>>>(
      Wgate, Wup, Wdown, Wc, Wg, bc, bg, wgu, wdb, Af, cf);
  k_stats<<<NB * NT / 4, 256, 0, stream>>>(x, ln_g, ln_b, Wg, Af, cf, aff, xb16, twt, cnt);
  k_topk<<<NB * NE * 4, 256, 0, stream>>>(aff, sidx, sval, twt, cnt, inv);
  dim3 gffn(NB * NE, 4096 / 64, 1);
  k_ffn<<<gffn, 256, 0, stream>>>(xb16, wgu, wdb, sidx, contrib);
  k_scatter<<<NB * NT, 256, 0, stream>>>(contrib, cnt, inv, sval, twt, out);
}